// Round 1
// baseline (201.452 us; speedup 1.0000x reference)
//
#include <hip/hip_runtime.h>

// Per-element MLP 1->32->(32x32)x9->1, leaky relu, v_mfma_f32_32x32x16_f16.
// R6: R5 was still ~4.5x off the ~9us throughput floor (MFMA 18.4k cyc/CU,
// VALU ~22k cyc/SIMD) with hbm at 4.8% -> latency-bound at 2 waves/SIMD
// (real reg use ~190: 72 resident weight VGPRs + 4x16 accs pinned occupancy).
// Fix: weights/bias/io fragments -> LDS (pre-permuted, contiguous b128 reads,
// ~12.5k LDS cyc/CU < MFMA floor), bias folded into lo-MFMA C operand (kills
// pk_add stage + replaces the 16 zero-C regs), chains processed in groups of
// 2 (only 32 acc regs live) -> peak ~115 VGPRs -> 4 waves/SIMD, grid 1024,
// exactly 2 iters/wave, cross-iter x prefetch kept.
#define NLAYERS 9
#define HID 32
#define SLOPE 0.01f

typedef _Float16 v2h __attribute__((ext_vector_type(2)));
typedef _Float16 v8h __attribute__((ext_vector_type(8)));
typedef float v16f __attribute__((ext_vector_type(16)));

#define NCHAIN 4

union U8 { v8h v; v2h p[4]; };           // B-operand half (16 f16 = 4 VGPRs)
struct U16 { v2h p[8]; };                // 32B of packed io-weight pairs

__device__ __forceinline__ v2h pk_cvt(float a, float b) {
    return __builtin_bit_cast(v2h, __builtin_amdgcn_cvt_pkrtz(a, b));
}
__device__ __forceinline__ v2h leaky2(v2h t, v2h s) {
    return __builtin_elementwise_max(t, t * s);
}
// B-operand physical slot k -> logical hidden unit (weight-side permutation)
__device__ __forceinline__ int qmap(int k) {
    int c = k >> 4, h = (k >> 3) & 1, t = k & 7;
    return 16 * c + 4 * h + (t & 3) + 8 * (t >> 2);
}
// C/D reg -> physical row
__device__ __forceinline__ int rmap(int reg, int h) {
    return (reg & 3) + 8 * (reg >> 2) + 4 * h;
}

__global__ __launch_bounds__(256, 4) void mlp_mfma_kernel(
    const float* __restrict__ x,
    const float* __restrict__ W_in,   // [1,32]
    const float* __restrict__ b_in,   // [32]
    const float* __restrict__ W_hid,  // [9,32,32]  W[l][k_in][n_out]
    const float* __restrict__ b_hid,  // [9,32]
    const float* __restrict__ W_out,  // [32,1]
    const float* __restrict__ b_out,  // [1]
    float* __restrict__ out, int N)
{
    // Pre-permuted per-lane weight fragments: lane reads 16B contiguous.
    __shared__ __align__(16) _Float16 wlo_sh[NLAYERS][64][8];  // 9 KiB
    __shared__ __align__(16) _Float16 whi_sh[NLAYERS][64][8];  // 9 KiB
    // f32 bias in MFMA C layout: reg r of half hf <- b_hid[rmap(r,hf)]
    __shared__ __align__(64) float bc_sh[NLAYERS][2][16];      // 1.1 KiB
    __shared__ __align__(32) v2h win_sh[2][8];
    __shared__ __align__(32) v2h bin_sh[2][8];
    __shared__ __align__(32) v2h wout_sh[2][8];

    const int tid = threadIdx.x;
    for (int t = tid; t < NLAYERS * 64; t += blockDim.x) {
        int l = t >> 6, ln = t & 63, hf = (ln >> 5) & 1, mm = ln & 31;
        const float* Wl = W_hid + l * HID * HID;
        v8h lo, hi;
#pragma unroll
        for (int j = 0; j < 8; ++j) {
            lo[j] = (_Float16)Wl[qmap(8 * hf + j) * HID + mm];
            hi[j] = (_Float16)Wl[qmap(16 + 8 * hf + j) * HID + mm];
        }
        *(v8h*)&wlo_sh[l][ln][0] = lo;
        *(v8h*)&whi_sh[l][ln][0] = hi;
    }
    for (int t = tid; t < NLAYERS * 32; t += blockDim.x) {
        int l = t >> 5, r = t & 31, hf = r >> 4, reg = r & 15;
        bc_sh[l][hf][reg] = b_hid[l * HID + rmap(reg, hf)];
    }
    if (tid < 16) {
        int hf = tid >> 3, u = tid & 7;
        int i0 = 2 * u, i1 = 2 * u + 1;
        int d0 = qmap(((i0 >> 3) << 4) + 8 * hf + (i0 & 7));
        int d1 = qmap(((i1 >> 3) << 4) + 8 * hf + (i1 & 7));
        win_sh[hf][u]  = v2h{(_Float16)W_in[d0],  (_Float16)W_in[d1]};
        bin_sh[hf][u]  = v2h{(_Float16)b_in[d0],  (_Float16)b_in[d1]};
        wout_sh[hf][u] = v2h{(_Float16)W_out[d0], (_Float16)W_out[d1]};
    }
    __syncthreads();

    const int lane = tid & 63;
    const int half = lane >> 5;
    const int m    = lane & 31;   // batch col within tile

    const float bo = b_out[0];
    const v2h slope2 = v2h{(_Float16)SLOPE, (_Float16)SLOPE};

    const int nwaves = (gridDim.x * blockDim.x) >> 6;
    const int wid    = (blockIdx.x * blockDim.x + tid) >> 6;
    const int niter  = (N + NCHAIN * 32 - 1) / (NCHAIN * 32);

    // ---- x prefetch for first iteration ----
    float xc[NCHAIN] = {0.0f, 0.0f, 0.0f, 0.0f};
    if (wid < niter) {
#pragma unroll
        for (int c = 0; c < NCHAIN; ++c) {
            int idx = wid * (NCHAIN * 32) + c * 32 + m;
            xc[c] = (idx < N) ? x[idx] : 0.0f;
        }
    }

    for (int it = wid; it < niter; it += nwaves) {
        // prefetch next iteration's x (hides HBM latency under compute)
        float xn[NCHAIN] = {0.0f, 0.0f, 0.0f, 0.0f};
        {
            int nit = it + nwaves;
            if (nit < niter) {
#pragma unroll
                for (int c = 0; c < NCHAIN; ++c) {
                    int idx = nit * (NCHAIN * 32) + c * 32 + m;
                    xn[c] = (idx < N) ? x[idx] : 0.0f;
                }
            }
        }

        // ---- input layer, all chains ----
        U8 clo[NCHAIN], chi[NCHAIN];
        {
            U16 wi = *(const U16*)&win_sh[half][0];
            U16 bi = *(const U16*)&bin_sh[half][0];
#pragma unroll
            for (int c = 0; c < NCHAIN; ++c) {
                _Float16 xh = (_Float16)xc[c];
                v2h x2 = v2h{xh, xh};
#pragma unroll
                for (int u = 0; u < 4; ++u) {
                    clo[c].p[u] = leaky2(x2 * wi.p[u] + bi.p[u], slope2);
                    chi[c].p[u] = leaky2(x2 * wi.p[4 + u] + bi.p[4 + u], slope2);
                }
            }
        }

        // ---- 9 hidden layers ----
#pragma unroll
        for (int l = 0; l < NLAYERS; ++l) {
            v8h wlo = *(const v8h*)&wlo_sh[l][lane][0];   // 1x ds_read_b128
            v8h whi = *(const v8h*)&whi_sh[l][lane][0];   // 1x ds_read_b128
            v16f bc = *(const v16f*)&bc_sh[l][half][0];   // 4x b128 broadcast
            // chains in groups of 2: only 2 accumulators (32 VGPRs) live,
            // groups are data-independent -> compiler can overlap epilogue(g)
            // with MFMAs(g+1); bias rides in the lo-MFMA C operand.
#pragma unroll
            for (int g = 0; g < NCHAIN / 2; ++g) {
                const int c0 = 2 * g, c1 = 2 * g + 1;
                v16f a0 = __builtin_amdgcn_mfma_f32_32x32x16_f16(wlo, clo[c0].v, bc, 0, 0, 0);
                v16f a1 = __builtin_amdgcn_mfma_f32_32x32x16_f16(wlo, clo[c1].v, bc, 0, 0, 0);
                a0 = __builtin_amdgcn_mfma_f32_32x32x16_f16(whi, chi[c0].v, a0, 0, 0, 0);
                a1 = __builtin_amdgcn_mfma_f32_32x32x16_f16(whi, chi[c1].v, a1, 0, 0, 0);
#pragma unroll
                for (int u = 0; u < 4; ++u) {
                    clo[c0].p[u] = leaky2(pk_cvt(a0[2 * u], a0[2 * u + 1]), slope2);
                    chi[c0].p[u] = leaky2(pk_cvt(a0[8 + 2 * u], a0[8 + 2 * u + 1]), slope2);
                    clo[c1].p[u] = leaky2(pk_cvt(a1[2 * u], a1[2 * u + 1]), slope2);
                    chi[c1].p[u] = leaky2(pk_cvt(a1[8 + 2 * u], a1[8 + 2 * u + 1]), slope2);
                }
            }
        }

        // ---- output layer ----
        {
            U16 wo = *(const U16*)&wout_sh[half][0];
#pragma unroll
            for (int c = 0; c < NCHAIN; ++c) {
                float p = 0.0f;
#pragma unroll
                for (int u = 0; u < 4; ++u) {
                    p = fmaf((float)clo[c].p[u][0], (float)wo.p[u][0], p);
                    p = fmaf((float)clo[c].p[u][1], (float)wo.p[u][1], p);
                    p = fmaf((float)chi[c].p[u][0], (float)wo.p[4 + u][0], p);
                    p = fmaf((float)chi[c].p[u][1], (float)wo.p[4 + u][1], p);
                }
                float o = p + __shfl_xor(p, 32, 64) + bo;   // full sum in all lanes
                int idx = it * (NCHAIN * 32) + c * 32 + m;
                // split the 4 stores across the two halves (2 per lane)
                if (half == (c >> 1) && idx < N) out[idx] = o;
            }
        }

#pragma unroll
        for (int c = 0; c < NCHAIN; ++c) xc[c] = xn[c];
    }
}

extern "C" void kernel_launch(void* const* d_in, const int* in_sizes, int n_in,
                              void* d_out, int out_size, void* d_ws, size_t ws_size,
                              hipStream_t stream) {
    const float* x     = (const float*)d_in[0];
    const float* W_in  = (const float*)d_in[1];
    const float* b_in  = (const float*)d_in[2];
    const float* W_hid = (const float*)d_in[3];
    const float* b_hid = (const float*)d_in[4];
    const float* W_out = (const float*)d_in[5];
    const float* b_out = (const float*)d_in[6];
    float* out = (float*)d_out;

    int N = in_sizes[0];
    // 1024 blocks x 4 waves = 4096 waves = 4 waves/SIMD resident (128-VGPR
    // cap via launch_bounds; ~20 KiB LDS/block -> 4 blocks/CU fits easily).
    // 8192 quad-tile iterations -> exactly 2 per wave, no ragged tail.
    dim3 block(256);
    dim3 grid(1024);
    mlp_mfma_kernel<<<grid, block, 0, stream>>>(x, W_in, b_in, W_hid, b_hid,
                                                W_out, b_out, out, N);
}

// Round 2
// 146.618 us; speedup vs baseline: 1.3740x; 1.3740x over previous
//
#include <hip/hip_runtime.h>

// Per-element MLP 1->32->(32x32)x9->1, leaky relu, v_mfma_f32_32x32x16_f16.
// R7: R6 forced 4 waves/SIMD via __launch_bounds__(256,4) (128-reg cap); the
// allocator split 64 arch-VGPR / 64 AGPR and spilled ~440 MB of scratch
// (FETCH 219 MB / WRITE 225 MB, 37% HBM) -> 153us steady. True liveness is
// ~116 regs, but hipcc won't pack tightly across the arch/acc split at the
// cap. Fix: keep the R6 structure (LDS pre-permuted weights = -72 persistent
// VGPRs, bias folded into lo-MFMA C operand, acc groups of 2) but cap at
// (256,3) -> 168-reg budget, grid 768 (exactly 3 blocks/CU, 58.5 KiB LDS/CU).
// 3 waves/SIMD x 4 chains = 12 independent chains/SIMD vs R5's 8, no spill.
#define NLAYERS 9
#define HID 32
#define SLOPE 0.01f

typedef _Float16 v2h __attribute__((ext_vector_type(2)));
typedef _Float16 v8h __attribute__((ext_vector_type(8)));
typedef float v16f __attribute__((ext_vector_type(16)));

#define NCHAIN 4

union U8 { v8h v; v2h p[4]; };           // B-operand half (16 f16 = 4 VGPRs)
struct U16 { v2h p[8]; };                // 32B of packed io-weight pairs

__device__ __forceinline__ v2h pk_cvt(float a, float b) {
    return __builtin_bit_cast(v2h, __builtin_amdgcn_cvt_pkrtz(a, b));
}
__device__ __forceinline__ v2h leaky2(v2h t, v2h s) {
    return __builtin_elementwise_max(t, t * s);
}
// B-operand physical slot k -> logical hidden unit (weight-side permutation)
__device__ __forceinline__ int qmap(int k) {
    int c = k >> 4, h = (k >> 3) & 1, t = k & 7;
    return 16 * c + 4 * h + (t & 3) + 8 * (t >> 2);
}
// C/D reg -> physical row
__device__ __forceinline__ int rmap(int reg, int h) {
    return (reg & 3) + 8 * (reg >> 2) + 4 * h;
}

__global__ __launch_bounds__(256, 3) void mlp_mfma_kernel(
    const float* __restrict__ x,
    const float* __restrict__ W_in,   // [1,32]
    const float* __restrict__ b_in,   // [32]
    const float* __restrict__ W_hid,  // [9,32,32]  W[l][k_in][n_out]
    const float* __restrict__ b_hid,  // [9,32]
    const float* __restrict__ W_out,  // [32,1]
    const float* __restrict__ b_out,  // [1]
    float* __restrict__ out, int N)
{
    // Pre-permuted per-lane weight fragments: lane reads 16B contiguous.
    __shared__ __align__(16) _Float16 wlo_sh[NLAYERS][64][8];  // 9 KiB
    __shared__ __align__(16) _Float16 whi_sh[NLAYERS][64][8];  // 9 KiB
    // f32 bias in MFMA C layout: reg r of half hf <- b_hid[rmap(r,hf)]
    __shared__ __align__(64) float bc_sh[NLAYERS][2][16];      // 1.1 KiB
    __shared__ __align__(32) v2h win_sh[2][8];
    __shared__ __align__(32) v2h bin_sh[2][8];
    __shared__ __align__(32) v2h wout_sh[2][8];

    const int tid = threadIdx.x;
    for (int t = tid; t < NLAYERS * 64; t += blockDim.x) {
        int l = t >> 6, ln = t & 63, hf = (ln >> 5) & 1, mm = ln & 31;
        const float* Wl = W_hid + l * HID * HID;
        v8h lo, hi;
#pragma unroll
        for (int j = 0; j < 8; ++j) {
            lo[j] = (_Float16)Wl[qmap(8 * hf + j) * HID + mm];
            hi[j] = (_Float16)Wl[qmap(16 + 8 * hf + j) * HID + mm];
        }
        *(v8h*)&wlo_sh[l][ln][0] = lo;
        *(v8h*)&whi_sh[l][ln][0] = hi;
    }
    for (int t = tid; t < NLAYERS * 32; t += blockDim.x) {
        int l = t >> 5, r = t & 31, hf = r >> 4, reg = r & 15;
        bc_sh[l][hf][reg] = b_hid[l * HID + rmap(reg, hf)];
    }
    if (tid < 16) {
        int hf = tid >> 3, u = tid & 7;
        int i0 = 2 * u, i1 = 2 * u + 1;
        int d0 = qmap(((i0 >> 3) << 4) + 8 * hf + (i0 & 7));
        int d1 = qmap(((i1 >> 3) << 4) + 8 * hf + (i1 & 7));
        win_sh[hf][u]  = v2h{(_Float16)W_in[d0],  (_Float16)W_in[d1]};
        bin_sh[hf][u]  = v2h{(_Float16)b_in[d0],  (_Float16)b_in[d1]};
        wout_sh[hf][u] = v2h{(_Float16)W_out[d0], (_Float16)W_out[d1]};
    }
    __syncthreads();

    const int lane = tid & 63;
    const int half = lane >> 5;
    const int m    = lane & 31;   // batch col within tile

    const float bo = b_out[0];
    const v2h slope2 = v2h{(_Float16)SLOPE, (_Float16)SLOPE};

    const int nwaves = (gridDim.x * blockDim.x) >> 6;
    const int wid    = (blockIdx.x * blockDim.x + tid) >> 6;
    const int niter  = (N + NCHAIN * 32 - 1) / (NCHAIN * 32);

    // ---- x prefetch for first iteration ----
    float xc[NCHAIN] = {0.0f, 0.0f, 0.0f, 0.0f};
    if (wid < niter) {
#pragma unroll
        for (int c = 0; c < NCHAIN; ++c) {
            int idx = wid * (NCHAIN * 32) + c * 32 + m;
            xc[c] = (idx < N) ? x[idx] : 0.0f;
        }
    }

    for (int it = wid; it < niter; it += nwaves) {
        // prefetch next iteration's x (hides HBM latency under compute)
        float xn[NCHAIN] = {0.0f, 0.0f, 0.0f, 0.0f};
        {
            int nit = it + nwaves;
            if (nit < niter) {
#pragma unroll
                for (int c = 0; c < NCHAIN; ++c) {
                    int idx = nit * (NCHAIN * 32) + c * 32 + m;
                    xn[c] = (idx < N) ? x[idx] : 0.0f;
                }
            }
        }

        // ---- input layer, all chains ----
        U8 clo[NCHAIN], chi[NCHAIN];
        {
            U16 wi = *(const U16*)&win_sh[half][0];
            U16 bi = *(const U16*)&bin_sh[half][0];
#pragma unroll
            for (int c = 0; c < NCHAIN; ++c) {
                _Float16 xh = (_Float16)xc[c];
                v2h x2 = v2h{xh, xh};
#pragma unroll
                for (int u = 0; u < 4; ++u) {
                    clo[c].p[u] = leaky2(x2 * wi.p[u] + bi.p[u], slope2);
                    chi[c].p[u] = leaky2(x2 * wi.p[4 + u] + bi.p[4 + u], slope2);
                }
            }
        }

        // ---- 9 hidden layers ----
#pragma unroll
        for (int l = 0; l < NLAYERS; ++l) {
            v8h wlo = *(const v8h*)&wlo_sh[l][lane][0];   // 1x ds_read_b128
            v8h whi = *(const v8h*)&whi_sh[l][lane][0];   // 1x ds_read_b128
            v16f bc = *(const v16f*)&bc_sh[l][half][0];   // 4x b128 broadcast
            // chains in groups of 2: only 2 accumulators (32 VGPRs) live,
            // groups are data-independent -> compiler can overlap epilogue(g)
            // with MFMAs(g+1); bias rides in the lo-MFMA C operand.
#pragma unroll
            for (int g = 0; g < NCHAIN / 2; ++g) {
                const int c0 = 2 * g, c1 = 2 * g + 1;
                v16f a0 = __builtin_amdgcn_mfma_f32_32x32x16_f16(wlo, clo[c0].v, bc, 0, 0, 0);
                v16f a1 = __builtin_amdgcn_mfma_f32_32x32x16_f16(wlo, clo[c1].v, bc, 0, 0, 0);
                a0 = __builtin_amdgcn_mfma_f32_32x32x16_f16(whi, chi[c0].v, a0, 0, 0, 0);
                a1 = __builtin_amdgcn_mfma_f32_32x32x16_f16(whi, chi[c1].v, a1, 0, 0, 0);
#pragma unroll
                for (int u = 0; u < 4; ++u) {
                    clo[c0].p[u] = leaky2(pk_cvt(a0[2 * u], a0[2 * u + 1]), slope2);
                    chi[c0].p[u] = leaky2(pk_cvt(a0[8 + 2 * u], a0[8 + 2 * u + 1]), slope2);
                    clo[c1].p[u] = leaky2(pk_cvt(a1[2 * u], a1[2 * u + 1]), slope2);
                    chi[c1].p[u] = leaky2(pk_cvt(a1[8 + 2 * u], a1[8 + 2 * u + 1]), slope2);
                }
            }
        }

        // ---- output layer ----
        {
            U16 wo = *(const U16*)&wout_sh[half][0];
#pragma unroll
            for (int c = 0; c < NCHAIN; ++c) {
                float p = 0.0f;
#pragma unroll
                for (int u = 0; u < 4; ++u) {
                    p = fmaf((float)clo[c].p[u][0], (float)wo.p[u][0], p);
                    p = fmaf((float)clo[c].p[u][1], (float)wo.p[u][1], p);
                    p = fmaf((float)chi[c].p[u][0], (float)wo.p[4 + u][0], p);
                    p = fmaf((float)chi[c].p[u][1], (float)wo.p[4 + u][1], p);
                }
                float o = p + __shfl_xor(p, 32, 64) + bo;   // full sum in all lanes
                int idx = it * (NCHAIN * 32) + c * 32 + m;
                // split the 4 stores across the two halves (2 per lane)
                if (half == (c >> 1) && idx < N) out[idx] = o;
            }
        }

#pragma unroll
        for (int c = 0; c < NCHAIN; ++c) xc[c] = xn[c];
    }
}

extern "C" void kernel_launch(void* const* d_in, const int* in_sizes, int n_in,
                              void* d_out, int out_size, void* d_ws, size_t ws_size,
                              hipStream_t stream) {
    const float* x     = (const float*)d_in[0];
    const float* W_in  = (const float*)d_in[1];
    const float* b_in  = (const float*)d_in[2];
    const float* W_hid = (const float*)d_in[3];
    const float* b_hid = (const float*)d_in[4];
    const float* W_out = (const float*)d_in[5];
    const float* b_out = (const float*)d_in[6];
    float* out = (float*)d_out;

    int N = in_sizes[0];
    // 768 blocks x 4 waves = 3072 waves = 3 waves/SIMD resident (168-reg
    // budget via launch_bounds(256,3); 19.5 KiB LDS/block x 3 = 58.5 KiB/CU).
    // 8192 quad-tile iterations -> 2-3 per wave.
    dim3 block(256);
    dim3 grid(768);
    mlp_mfma_kernel<<<grid, block, 0, stream>>>(x, W_in, b_in, W_hid, b_hid,
                                                W_out, b_out, out, N);
}

// Round 3
// 102.288 us; speedup vs baseline: 1.9695x; 1.4334x over previous
//
#include <hip/hip_runtime.h>

// Per-element MLP 1->32->(32x32)x9->1, leaky relu, v_mfma_f32_32x32x16_f16.
// R8: R6/R7 (LDS-resident weights + reg cap for occupancy) both spilled
// ~300-440MB scratch: full 9-layer unroll hoists the per-layer ds_reads
// (~216 regs of LDS results) past any cap -> allocator spills instead of
// packing. Revert to R5's proven spill-free structure (weights VGPR-resident,
// (256,2), 2 waves/SIMD) and raise in-wave ILP instead: NCHAIN 4->6
// (12 independent chains/SIMD), accumulators grouped 2-at-a-time (32 acc
// regs live, 3 independent groups/layer -> epilogue(g) overlaps MFMA(g+1)).
// Reg estimate ~208/256 budget - inside the proven-safe region.
#define NLAYERS 9
#define HID 32
#define SLOPE 0.01f

typedef _Float16 v2h __attribute__((ext_vector_type(2)));
typedef _Float16 v8h __attribute__((ext_vector_type(8)));
typedef float v16f __attribute__((ext_vector_type(16)));

#define NCHAIN 6

union U8 { v8h v; v2h p[4]; };          // B-operand half (16 f16 = 4 VGPRs)
struct B4 { v2h a, b, c, d; };           // 16B of packed bias

__device__ __forceinline__ v2h pk_cvt(float a, float b) {
    return __builtin_bit_cast(v2h, __builtin_amdgcn_cvt_pkrtz(a, b));
}
__device__ __forceinline__ v2h leaky2(v2h t, v2h s) {
    return __builtin_elementwise_max(t, t * s);
}
// B-operand physical slot k -> logical hidden unit (weight-side permutation)
__device__ __forceinline__ int qmap(int k) {
    int c = k >> 4, h = (k >> 3) & 1, t = k & 7;
    return 16 * c + 4 * h + (t & 3) + 8 * (t >> 2);
}
// C/D reg -> physical row
__device__ __forceinline__ int rmap(int reg, int h) {
    return (reg & 3) + 8 * (reg >> 2) + 4 * h;
}

__global__ __launch_bounds__(256, 2) void mlp_mfma_kernel(
    const float* __restrict__ x,
    const float* __restrict__ W_in,   // [1,32]
    const float* __restrict__ b_in,   // [32]
    const float* __restrict__ W_hid,  // [9,32,32]  W[l][k_in][n_out]
    const float* __restrict__ b_hid,  // [9,32]
    const float* __restrict__ W_out,  // [32,1]
    const float* __restrict__ b_out,  // [1]
    float* __restrict__ out, int N)
{
    // packed f16 bias: [layer][half][j], pair j covers C regs (2j, 2j+1)
    __shared__ __align__(16) v2h bias_sh[NLAYERS][2][8];
    for (int t = threadIdx.x; t < NLAYERS * 16; t += blockDim.x) {
        int l = t >> 4, r = t & 15, h = r >> 3, j = r & 7;
        bias_sh[l][h][j] = v2h{(_Float16)b_hid[l * HID + rmap(2 * j, h)],
                               (_Float16)b_hid[l * HID + rmap(2 * j + 1, h)]};
    }
    __syncthreads();

    const int lane = threadIdx.x & 63;
    const int half = lane >> 5;
    const int m    = lane & 31;   // batch col within tile; also A output-row

    // ---- resident weight fragments (72 VGPRs) ----
    v8h alo[NLAYERS], ahi[NLAYERS];
#pragma unroll
    for (int l = 0; l < NLAYERS; ++l) {
        const float* Wl = W_hid + l * HID * HID;
#pragma unroll
        for (int j = 0; j < 8; ++j) {
            alo[l][j] = (_Float16)Wl[qmap(8 * half + j) * HID + m];
            ahi[l][j] = (_Float16)Wl[qmap(16 + 8 * half + j) * HID + m];
        }
    }
    v2h win2[8], bin2[8], wout2[8];
#pragma unroll
    for (int u = 0; u < 8; ++u) {
        int i0 = 2 * u, i1 = 2 * u + 1;
        int d0 = qmap(((i0 >> 3) << 4) + 8 * half + (i0 & 7));
        int d1 = qmap(((i1 >> 3) << 4) + 8 * half + (i1 & 7));
        win2[u]  = v2h{(_Float16)W_in[d0],  (_Float16)W_in[d1]};
        bin2[u]  = v2h{(_Float16)b_in[d0],  (_Float16)b_in[d1]};
        wout2[u] = v2h{(_Float16)W_out[d0], (_Float16)W_out[d1]};
    }
    const float bo = b_out[0];
    const v2h slope2 = v2h{(_Float16)SLOPE, (_Float16)SLOPE};
    const v16f z16 = {};   // zero C operand (never rewritten)

    const int nwaves = (gridDim.x * blockDim.x) >> 6;
    const int wid    = (blockIdx.x * blockDim.x + threadIdx.x) >> 6;
    const int niter  = (N + NCHAIN * 32 - 1) / (NCHAIN * 32);

    // ---- x prefetch for first iteration ----
    float xc[NCHAIN];
#pragma unroll
    for (int c = 0; c < NCHAIN; ++c) xc[c] = 0.0f;
    if (wid < niter) {
#pragma unroll
        for (int c = 0; c < NCHAIN; ++c) {
            int idx = wid * (NCHAIN * 32) + c * 32 + m;
            xc[c] = (idx < N) ? x[idx] : 0.0f;
        }
    }

    for (int it = wid; it < niter; it += nwaves) {
        // prefetch next iteration's x (hides ~900cyc HBM latency under compute)
        float xn[NCHAIN];
#pragma unroll
        for (int c = 0; c < NCHAIN; ++c) xn[c] = 0.0f;
        {
            int nit = it + nwaves;
            if (nit < niter) {
#pragma unroll
                for (int c = 0; c < NCHAIN; ++c) {
                    int idx = nit * (NCHAIN * 32) + c * 32 + m;
                    xn[c] = (idx < N) ? x[idx] : 0.0f;
                }
            }
        }

        // ---- input layer, all chains ----
        U8 clo[NCHAIN], chi[NCHAIN];
#pragma unroll
        for (int c = 0; c < NCHAIN; ++c) {
            _Float16 xh = (_Float16)xc[c];
            v2h x2 = v2h{xh, xh};
#pragma unroll
            for (int u = 0; u < 4; ++u) {
                clo[c].p[u] = leaky2(x2 * win2[u] + bin2[u], slope2);
                chi[c].p[u] = leaky2(x2 * win2[4 + u] + bin2[4 + u], slope2);
            }
        }

        // ---- 9 hidden layers ----
#pragma unroll
        for (int l = 0; l < NLAYERS; ++l) {
            B4 q0 = __builtin_bit_cast(B4, ((const uint4*)&bias_sh[l][half][0])[0]);
            B4 q1 = __builtin_bit_cast(B4, ((const uint4*)&bias_sh[l][half][4])[0]);
            v2h bl[8] = {q0.a, q0.b, q0.c, q0.d, q1.a, q1.b, q1.c, q1.d};
            // chains in groups of 2: only 2 accumulators (32 regs) live; the
            // 3 groups are independent -> scheduler overlaps epilogue(g) with
            // MFMAs(g+1). lo->hi C-operand dep is pipelined acc-forwarding.
#pragma unroll
            for (int g = 0; g < NCHAIN / 2; ++g) {
                const int c0 = 2 * g, c1 = 2 * g + 1;
                v16f a0 = __builtin_amdgcn_mfma_f32_32x32x16_f16(alo[l], clo[c0].v, z16, 0, 0, 0);
                v16f a1 = __builtin_amdgcn_mfma_f32_32x32x16_f16(alo[l], clo[c1].v, z16, 0, 0, 0);
                a0 = __builtin_amdgcn_mfma_f32_32x32x16_f16(ahi[l], chi[c0].v, a0, 0, 0, 0);
                a1 = __builtin_amdgcn_mfma_f32_32x32x16_f16(ahi[l], chi[c1].v, a1, 0, 0, 0);
#pragma unroll
                for (int u = 0; u < 4; ++u) {
                    clo[c0].p[u] = leaky2(pk_cvt(a0[2 * u], a0[2 * u + 1]) + bl[u], slope2);
                    chi[c0].p[u] = leaky2(pk_cvt(a0[8 + 2 * u], a0[8 + 2 * u + 1]) + bl[4 + u], slope2);
                    clo[c1].p[u] = leaky2(pk_cvt(a1[2 * u], a1[2 * u + 1]) + bl[u], slope2);
                    chi[c1].p[u] = leaky2(pk_cvt(a1[8 + 2 * u], a1[8 + 2 * u + 1]) + bl[4 + u], slope2);
                }
            }
        }

        // ---- output layer ----
#pragma unroll
        for (int c = 0; c < NCHAIN; ++c) {
            float p = 0.0f;
#pragma unroll
            for (int u = 0; u < 4; ++u) {
                p = fmaf((float)clo[c].p[u][0], (float)wout2[u][0], p);
                p = fmaf((float)clo[c].p[u][1], (float)wout2[u][1], p);
                p = fmaf((float)chi[c].p[u][0], (float)wout2[4 + u][0], p);
                p = fmaf((float)chi[c].p[u][1], (float)wout2[4 + u][1], p);
            }
            float o = p + __shfl_xor(p, 32, 64) + bo;   // full sum in all lanes
            int idx = it * (NCHAIN * 32) + c * 32 + m;
            // split the 6 stores across the two halves (3 per lane)
            if (half == (c & 1) && idx < N) out[idx] = o;
        }

#pragma unroll
        for (int c = 0; c < NCHAIN; ++c) xc[c] = xn[c];
    }
}

extern "C" void kernel_launch(void* const* d_in, const int* in_sizes, int n_in,
                              void* d_out, int out_size, void* d_ws, size_t ws_size,
                              hipStream_t stream) {
    const float* x     = (const float*)d_in[0];
    const float* W_in  = (const float*)d_in[1];
    const float* b_in  = (const float*)d_in[2];
    const float* W_hid = (const float*)d_in[3];
    const float* b_hid = (const float*)d_in[4];
    const float* W_out = (const float*)d_in[5];
    const float* b_out = (const float*)d_in[6];
    float* out = (float*)d_out;

    int N = in_sizes[0];
    // 512 blocks x 4 waves = 2048 waves = 2 waves/SIMD resident (256-reg
    // budget, proven spill-free region). niter = ceil(N/192) = 5462 ->
    // ~2.67 iterations/wave; weights stay VGPR-resident.
    dim3 block(256);
    dim3 grid(512);
    mlp_mfma_kernel<<<grid, block, 0, stream>>>(x, W_in, b_in, W_hid, b_hid,
                                                W_out, b_out, out, N);
}

// Round 4
// 89.917 us; speedup vs baseline: 2.2404x; 1.1376x over previous
//
#include <hip/hip_runtime.h>

// Per-element MLP 1->32->(32x32)x9->1, leaky relu, v_mfma_f32_32x32x16_f16.
// R9: R8 (NCHAIN=6, reg-resident weights) == R5 (42.9us): the 2 extra chains
// spilled (~15 regs/lane/iter scratch, WRITE 28.5MB) and ate the ILP gain;
// the structure is pinned at 2 waves/SIMD (VALUBusy 42%, latency-bound).
// R6/R7's LDS-weights spill was caused by FULL UNROLL of the layer loop
// (LLVM hoisted 54 ds_reads -> +200 liveness), not by LDS itself. Fix:
// LDS pre-permuted weights + '#pragma unroll 1' layer loop -> per-layer
// ds_reads stay in the loop, true liveness ~140 regs. NCHAIN=4, bias folded
// into lo-MFMA C operand (f32 C-layout, -25% epilogue VALU), (256,3) ->
// 3 waves/SIMD, grid 768 (3 blocks/CU, 58.8 KiB LDS/CU).
// Floors: VALU 5.3us/SIMD, LDS 5.8us/CU, MFMA 1.3us -> latency-limited.
#define NLAYERS 9
#define HID 32
#define SLOPE 0.01f

typedef _Float16 v2h __attribute__((ext_vector_type(2)));
typedef _Float16 v8h __attribute__((ext_vector_type(8)));
typedef float v16f __attribute__((ext_vector_type(16)));

#define NCHAIN 4

union U8 { v8h v; v2h p[4]; };          // B-operand half (16 f16 = 4 VGPRs)

__device__ __forceinline__ v2h pk_cvt(float a, float b) {
    return __builtin_bit_cast(v2h, __builtin_amdgcn_cvt_pkrtz(a, b));
}
__device__ __forceinline__ v2h leaky2(v2h t, v2h s) {
    return __builtin_elementwise_max(t, t * s);
}
// B-operand physical slot k -> logical hidden unit (weight-side permutation)
__device__ __forceinline__ int qmap(int k) {
    int c = k >> 4, h = (k >> 3) & 1, t = k & 7;
    return 16 * c + 4 * h + (t & 3) + 8 * (t >> 2);
}
// C/D reg -> physical row
__device__ __forceinline__ int rmap(int reg, int h) {
    return (reg & 3) + 8 * (reg >> 2) + 4 * h;
}

__global__ __launch_bounds__(256, 3) void mlp_mfma_kernel(
    const float* __restrict__ x,
    const float* __restrict__ W_in,   // [1,32]
    const float* __restrict__ b_in,   // [32]
    const float* __restrict__ W_hid,  // [9,32,32]  W[l][k_in][n_out]
    const float* __restrict__ b_hid,  // [9,32]
    const float* __restrict__ W_out,  // [32,1]
    const float* __restrict__ b_out,  // [1]
    float* __restrict__ out, int N)
{
    // Pre-permuted per-lane weight fragments: lane reads 16B contiguous
    // (64 lanes x 16B = 1024B -> conflict-free, verified 0 conflicts in R7).
    __shared__ __align__(16) _Float16 wlo_sh[NLAYERS][64][8];  // 9 KiB
    __shared__ __align__(16) _Float16 whi_sh[NLAYERS][64][8];  // 9 KiB
    // f32 bias in MFMA C layout: reg r of half hf <- b_hid[rmap(r,hf)]
    __shared__ __align__(64) float bc_sh[NLAYERS][2][16];      // 1.1 KiB

    const int tid = threadIdx.x;
    for (int t = tid; t < NLAYERS * 64; t += blockDim.x) {
        int l = t >> 6, ln = t & 63, hf = (ln >> 5) & 1, mm = ln & 31;
        const float* Wl = W_hid + l * HID * HID;
        v8h lo, hi;
#pragma unroll
        for (int j = 0; j < 8; ++j) {
            lo[j] = (_Float16)Wl[qmap(8 * hf + j) * HID + mm];
            hi[j] = (_Float16)Wl[qmap(16 + 8 * hf + j) * HID + mm];
        }
        *(v8h*)&wlo_sh[l][ln][0] = lo;
        *(v8h*)&whi_sh[l][ln][0] = hi;
    }
    for (int t = tid; t < NLAYERS * 32; t += blockDim.x) {
        int l = t >> 5, r = t & 31, hf = r >> 4, reg = r & 15;
        bc_sh[l][hf][reg] = b_hid[l * HID + rmap(reg, hf)];
    }
    __syncthreads();

    const int lane = tid & 63;
    const int half = lane >> 5;
    const int m    = lane & 31;   // batch col within tile

    // ---- register-resident io-layer fragments (24 VGPRs) ----
    v2h win2[8], bin2[8], wout2[8];
#pragma unroll
    for (int u = 0; u < 8; ++u) {
        int i0 = 2 * u, i1 = 2 * u + 1;
        int d0 = qmap(((i0 >> 3) << 4) + 8 * half + (i0 & 7));
        int d1 = qmap(((i1 >> 3) << 4) + 8 * half + (i1 & 7));
        win2[u]  = v2h{(_Float16)W_in[d0],  (_Float16)W_in[d1]};
        bin2[u]  = v2h{(_Float16)b_in[d0],  (_Float16)b_in[d1]};
        wout2[u] = v2h{(_Float16)W_out[d0], (_Float16)W_out[d1]};
    }
    const float bo = b_out[0];
    const v2h slope2 = v2h{(_Float16)SLOPE, (_Float16)SLOPE};

    const int nwaves = (gridDim.x * blockDim.x) >> 6;
    const int wid    = (blockIdx.x * blockDim.x + tid) >> 6;
    const int niter  = (N + NCHAIN * 32 - 1) / (NCHAIN * 32);

    // ---- x prefetch for first iteration ----
    float xc[NCHAIN] = {0.0f, 0.0f, 0.0f, 0.0f};
    if (wid < niter) {
#pragma unroll
        for (int c = 0; c < NCHAIN; ++c) {
            int idx = wid * (NCHAIN * 32) + c * 32 + m;
            xc[c] = (idx < N) ? x[idx] : 0.0f;
        }
    }

    for (int it = wid; it < niter; it += nwaves) {
        // prefetch next iteration's x (hides HBM latency under compute)
        float xn[NCHAIN] = {0.0f, 0.0f, 0.0f, 0.0f};
        {
            int nit = it + nwaves;
            if (nit < niter) {
#pragma unroll
                for (int c = 0; c < NCHAIN; ++c) {
                    int idx = nit * (NCHAIN * 32) + c * 32 + m;
                    xn[c] = (idx < N) ? x[idx] : 0.0f;
                }
            }
        }

        // ---- input layer, all chains ----
        U8 clo[NCHAIN], chi[NCHAIN];
#pragma unroll
        for (int c = 0; c < NCHAIN; ++c) {
            _Float16 xh = (_Float16)xc[c];
            v2h x2 = v2h{xh, xh};
#pragma unroll
            for (int u = 0; u < 4; ++u) {
                clo[c].p[u] = leaky2(x2 * win2[u] + bin2[u], slope2);
                chi[c].p[u] = leaky2(x2 * win2[4 + u] + bin2[4 + u], slope2);
            }
        }

        // ---- 9 hidden layers: REAL loop (no unroll) so per-layer ds_reads
        // cannot be hoisted/inflate liveness (the R6/R7 spill cause) ----
#pragma unroll 1
        for (int l = 0; l < NLAYERS; ++l) {
            v8h wlo = *(const v8h*)&wlo_sh[l][lane][0];   // 1x ds_read_b128
            v8h whi = *(const v8h*)&whi_sh[l][lane][0];   // 1x ds_read_b128
            v16f bc = *(const v16f*)&bc_sh[l][half][0];   // 4x b128 broadcast
            // chains in groups of 2: 32 acc regs live; 2 independent groups
            // -> epilogue(g) overlaps MFMAs(g+1); bias rides in lo-MFMA C.
#pragma unroll
            for (int g = 0; g < NCHAIN / 2; ++g) {
                const int c0 = 2 * g, c1 = 2 * g + 1;
                v16f a0 = __builtin_amdgcn_mfma_f32_32x32x16_f16(wlo, clo[c0].v, bc, 0, 0, 0);
                v16f a1 = __builtin_amdgcn_mfma_f32_32x32x16_f16(wlo, clo[c1].v, bc, 0, 0, 0);
                a0 = __builtin_amdgcn_mfma_f32_32x32x16_f16(whi, chi[c0].v, a0, 0, 0, 0);
                a1 = __builtin_amdgcn_mfma_f32_32x32x16_f16(whi, chi[c1].v, a1, 0, 0, 0);
#pragma unroll
                for (int u = 0; u < 4; ++u) {
                    clo[c0].p[u] = leaky2(pk_cvt(a0[2 * u], a0[2 * u + 1]), slope2);
                    chi[c0].p[u] = leaky2(pk_cvt(a0[8 + 2 * u], a0[8 + 2 * u + 1]), slope2);
                    clo[c1].p[u] = leaky2(pk_cvt(a1[2 * u], a1[2 * u + 1]), slope2);
                    chi[c1].p[u] = leaky2(pk_cvt(a1[8 + 2 * u], a1[8 + 2 * u + 1]), slope2);
                }
            }
        }

        // ---- output layer ----
#pragma unroll
        for (int c = 0; c < NCHAIN; ++c) {
            float p = 0.0f;
#pragma unroll
            for (int u = 0; u < 4; ++u) {
                p = fmaf((float)clo[c].p[u][0], (float)wout2[u][0], p);
                p = fmaf((float)clo[c].p[u][1], (float)wout2[u][1], p);
                p = fmaf((float)chi[c].p[u][0], (float)wout2[4 + u][0], p);
                p = fmaf((float)chi[c].p[u][1], (float)wout2[4 + u][1], p);
            }
            float o = p + __shfl_xor(p, 32, 64) + bo;   // full sum in all lanes
            int idx = it * (NCHAIN * 32) + c * 32 + m;
            // split the 4 stores across the two halves (2 per lane)
            if (half == (c >> 1) && idx < N) out[idx] = o;
        }

#pragma unroll
        for (int c = 0; c < NCHAIN; ++c) xc[c] = xn[c];
    }
}

extern "C" void kernel_launch(void* const* d_in, const int* in_sizes, int n_in,
                              void* d_out, int out_size, void* d_ws, size_t ws_size,
                              hipStream_t stream) {
    const float* x     = (const float*)d_in[0];
    const float* W_in  = (const float*)d_in[1];
    const float* b_in  = (const float*)d_in[2];
    const float* W_hid = (const float*)d_in[3];
    const float* b_hid = (const float*)d_in[4];
    const float* W_out = (const float*)d_in[5];
    const float* b_out = (const float*)d_in[6];
    float* out = (float*)d_out;

    int N = in_sizes[0];
    // 768 blocks x 4 waves = 3072 waves = 3 waves/SIMD (168-reg budget,
    // true liveness ~140 with the rolled layer loop; 19.6 KiB LDS x 3 = 58.8
    // KiB/CU). niter = 8192 -> 2-3 iterations/wave.
    dim3 block(256);
    dim3 grid(768);
    mlp_mfma_kernel<<<grid, block, 0, stream>>>(x, W_in, b_in, W_hid, b_hid,
                                                W_out, b_out, out, N);
}